// Round 5
// baseline (501.848 us; speedup 1.0000x reference)
//
#include <hip/hip_runtime.h>
#include <cstdint>
#include <cstddef>

// FlowNet-C correlation, MI355X round-4: bf16 MFMA banded-GEMM path.
// B=8 C=256 H=64 W=96, PAD=MAXD=20, K=1, S1=1, S2=2 -> 441 output channels.
// out[b, dy*21+dx, y, x] = (1/256) * sum_c in1[b,c,y,x] * in2[b,c,y+2(dy-10), x+2(dx-10)]
//
// R4: fp32 scheme is LDS-BW bound (12.7 GB LDS reads / 52 TB/s = 243 us floor;
// measured VALUBusy 32% == 1/3 oversubscription). Pivot:
//  parity split x=2u+p: out[u,dx] = sum_c A_p[u][c] * W_p[c][u+dx] -> banded GEMM,
//  16x16x32 bf16 MFMA tiles, dx = n-u band extracted in epilogue.
// Kernel 1 converts/transposes inputs to bf16 k-contiguous layouts in d_ws (64 MiB);
// falls back to the known-good fp32 kernel if ws_size < 64 MiB.

constexpr int B_ = 8, C_ = 256, H_ = 64, W_ = 96;
constexpr int D_ = 21;

typedef __attribute__((ext_vector_type(8))) short short8;
typedef __attribute__((ext_vector_type(4))) float f32x4;

__device__ __forceinline__ short f2bf(float f) {
    unsigned u = __builtin_bit_cast(unsigned, f);
    u += 0x7FFFu + ((u >> 16) & 1u);          // RNE (inputs are finite normals)
    return (short)(u >> 16);
}

// ---------------------------------------------------------------------------
// Kernel 1: convert + transpose.
// wsA[b][y][p][u][c]  (u=x>>1, p=x&1), shorts, 8*64*2*48*256 = 25,165,824 B
// wsW[b][y2][p][v][c] (v in [0,80), x2 = 2*(v-10)+p; 0 outside [0,96)),
//                     shorts, 8*64*2*80*256 = 41,943,040 B
// Blocks [0,2048): A-part (b,y,ctile); [2048,4096): W-part (b,y2,ctile).
// ---------------------------------------------------------------------------
__global__ __launch_bounds__(256) void convert_kernel(
    const float* __restrict__ in1, const float* __restrict__ in2,
    short* __restrict__ wsA, short* __restrict__ wsW)
{
    __shared__ float t[64][97];   // 64 channels x 96 cols (+1 pad)

    const int id  = blockIdx.x;
    const bool isW = id >= 2048;
    const int jid = isW ? id - 2048 : id;
    const int ct = jid & 3;
    const int y  = (jid >> 2) & 63;
    const int b  = jid >> 8;
    const int c0 = ct * 64;
    const int tid = threadIdx.x;

    const float* src = (isW ? in2 : in1) + ((size_t)(b * 256 + c0) * 64 + y) * 96;

    #pragma unroll
    for (int i = 0; i < 6; ++i) {
        int s = tid + 256 * i;              // 1536 slots: 64 rows x 24 float4
        int c = s / 24, xq = s - c * 24;
        float4 v = *(const float4*)(src + (size_t)c * (64 * 96) + xq * 4);
        t[c][xq * 4 + 0] = v.x; t[c][xq * 4 + 1] = v.y;
        t[c][xq * 4 + 2] = v.z; t[c][xq * 4 + 3] = v.w;
    }
    __syncthreads();

    union PK { short s[8]; int4 v; };

    if (!isW) {
        #pragma unroll
        for (int i = 0; i < 3; ++i) {
            int s2 = tid + 256 * i;         // 768 slots: 96 x * 8 seg
            int x = s2 >> 3, seg = s2 & 7;
            PK pk;
            #pragma unroll
            for (int j = 0; j < 8; ++j) pk.s[j] = f2bf(t[seg * 8 + j][x]);
            size_t off = ((((size_t)b * 64 + y) * 2 + (x & 1)) * 48 + (x >> 1)) * 256
                         + c0 + seg * 8;
            *(int4*)(wsA + off) = pk.v;
        }
    } else {
        #pragma unroll
        for (int i = 0; i < 5; ++i) {
            int s2 = tid + 256 * i;         // 1280 slots: 2 p * 80 v * 8 seg
            int p = s2 / 640; int r2 = s2 - p * 640;
            int v = r2 >> 3, seg = r2 & 7;
            int x2 = 2 * (v - 10) + p;
            PK pk;
            if (x2 >= 0 && x2 < 96) {
                #pragma unroll
                for (int j = 0; j < 8; ++j) pk.s[j] = f2bf(t[seg * 8 + j][x2]);
            } else {
                #pragma unroll
                for (int j = 0; j < 8; ++j) pk.s[j] = 0;
            }
            size_t off = ((((size_t)b * 64 + y) * 2 + p) * 80 + v) * 256
                         + c0 + seg * 8;
            *(int4*)(wsW + off) = pk.v;
        }
    }
}

// ---------------------------------------------------------------------------
// Kernel 2: banded MFMA GEMM.
// Block = (b, y, p, dyg); dyg covers 7 dy. 256 threads = 4 waves;
// waves own whole dys: w<3 -> {2w,2w+1}, w=3 -> {6}.
// Per dy: 3 M-tiles (u0=16m) x 3 band N-tiles (n0=u0+16s) -> 9 C-tiles.
// K-loop: 8 chunks of 32 channels staged into LDS (k-contiguous rows, 80 B stride).
// ---------------------------------------------------------------------------
__global__ __launch_bounds__(256, 2) void corr_mfma(
    const short* __restrict__ wsA, const short* __restrict__ wsW,
    float* __restrict__ out)
{
    __shared__ alignas(16) short a_s[48][40];       // 3.84 KB (cols [32,40) pad)
    __shared__ alignas(16) short w_s[7][80][40];    // 44.8 KB

    const int id = blockIdx.x;
    const int b = id & 7;
    int t = id >> 3;
    const int p = t & 1; t >>= 1;
    const int dyg = t % 3;
    const int y = t / 3;
    const int tid = threadIdx.x;
    const int wave = tid >> 6;
    const int lane = tid & 63;
    const int col = lane & 15;
    const int quad = lane >> 4;

    // zero LDS once: invalid-dy slabs must read as zeros; pads cleared too
    for (int i = tid; i < 7 * 80 * 40 / 8; i += 256) ((int4*)w_s)[i] = int4{0, 0, 0, 0};
    for (int i = tid; i < 48 * 40 / 8; i += 256)     ((int4*)a_s)[i] = int4{0, 0, 0, 0};

    // ---- staging descriptors ----
    // A: 192 slots (u=tid>>2, seg=tid&3)
    const bool hasA = tid < 192;
    const short* gA = wsA + ((((size_t)b * 64 + y) * 2 + p) * 48 + (tid >> 2)) * 256
                      + (tid & 3) * 8;
    short* lA = &a_s[tid >> 2][(tid & 3) * 8];
    // W: 2240 slots (dyl, v, seg) -> 9 per thread
    bool hasW[9]; const short* gW[9]; short* lW[9];
    #pragma unroll
    for (int i = 0; i < 9; ++i) {
        int s = tid + 256 * i;
        bool ok = s < 7 * 80 * 4;
        int sc = ok ? s : 0;
        int dyl = sc / 320; int r2 = sc - dyl * 320;
        int v = r2 >> 2, seg = r2 & 3;
        int y2 = y + 2 * (dyg * 7 + dyl) - 20;
        ok = ok && y2 >= 0 && y2 < 64;
        gW[i] = wsW + ((((size_t)b * 64 + (ok ? y2 : 0)) * 2 + p) * 80 + v) * 256 + seg * 8;
        lW[i] = &w_s[dyl][v][seg * 8];
        hasW[i] = ok;
    }

    f32x4 zero4 = {0.f, 0.f, 0.f, 0.f};
    f32x4 acc[2][3][3];
    #pragma unroll
    for (int i = 0; i < 2; ++i)
        #pragma unroll
        for (int m = 0; m < 3; ++m)
            #pragma unroll
            for (int s = 0; s < 3; ++s) acc[i][m][s] = zero4;

    for (int kc = 0; kc < 8; ++kc) {
        const int k0 = kc * 32;
        int4 bufA; int4 bufW[9];
        if (hasA) bufA = *(const int4*)(gA + k0);
        #pragma unroll
        for (int i = 0; i < 9; ++i)
            if (hasW[i]) bufW[i] = *(const int4*)(gW[i] + k0);

        __syncthreads();   // previous chunk's frag reads done (and zero-fill at kc=0)
        if (hasA) *(int4*)lA = bufA;
        #pragma unroll
        for (int i = 0; i < 9; ++i)
            if (hasW[i]) *(int4*)lW[i] = bufW[i];
        __syncthreads();   // staging visible

        short8 afr[3];
        #pragma unroll
        for (int m = 0; m < 3; ++m)
            afr[m] = *(const short8*)&a_s[m * 16 + col][quad * 8];

        #pragma unroll
        for (int dyi = 0; dyi < 2; ++dyi) {
            const int dyl = wave * 2 + dyi;   // waves: {0,1},{2,3},{4,5},{6,-}
            if (dyl > 6) break;               // wave-uniform
            short8 bfr[5];
            #pragma unroll
            for (int nt = 0; nt < 5; ++nt)
                bfr[nt] = *(const short8*)&w_s[dyl][nt * 16 + col][quad * 8];
            #pragma unroll
            for (int m = 0; m < 3; ++m)
                #pragma unroll
                for (int s = 0; s < 3; ++s)
                    acc[dyi][m][s] = __builtin_amdgcn_mfma_f32_16x16x32_bf16(
                        afr[m], bfr[m + s], acc[dyi][m][s], 0, 0, 0);
        }
    }

    // ---- epilogue: band extraction dx = n - u, scaled store ----
    const float sc = 1.0f / 256.0f;
    #pragma unroll
    for (int dyi = 0; dyi < 2; ++dyi) {
        const int dyl = wave * 2 + dyi;
        if (dyl > 6) break;
        const int dy = dyg * 7 + dyl;
        #pragma unroll
        for (int m = 0; m < 3; ++m)
            #pragma unroll
            for (int s = 0; s < 3; ++s)
                #pragma unroll
                for (int rr = 0; rr < 4; ++rr) {
                    const int u = m * 16 + quad * 4 + rr;     // C/D: row=quad*4+reg
                    const int dx = s * 16 + col - (quad * 4 + rr);  // col=lane&15
                    if (dx >= 0 && dx < 21) {
                        const int x = 2 * u + p;
                        size_t off = (((size_t)(b * 441 + dy * 21 + dx)) * 64 + y) * 96 + x;
                        out[off] = acc[dyi][m][s][rr] * sc;
                    }
                }
    }
}

// ---------------------------------------------------------------------------
// Fallback (ws too small): round-2 fp32 kernel, known-passing at ~363 us.
// ---------------------------------------------------------------------------
constexpr int CH = 4;
constexpr int NROW = 3;
constexpr int NDYG = 7;
constexpr int S2COLS = 164;
constexpr int THREADS = 128;

__global__ __launch_bounds__(THREADS, 4) void corr_fp32(
    const float* __restrict__ in1,
    const float* __restrict__ in2,
    float* __restrict__ out)
{
    __shared__ alignas(16) float s1[CH][W_];
    __shared__ alignas(16) float s2[CH][NROW][S2COLS];

    const int id  = blockIdx.x;
    const int b   = id & 7;
    const int s   = id >> 3;
    const int y   = s / NDYG;
    const int dyg = s - y * NDYG;
    const int tid = threadIdx.x;

    for (int u = tid; u < CH * NROW * 17; u += THREADS) {
        int j = u / (NROW * 17);
        int v = u - j * (NROW * 17);
        int r = v / 17;
        int p = v - r * 17;
        int col4 = (p < 5) ? p : (p + 24);
        ((float4*)&s2[j][r][0])[col4] = float4{0.f, 0.f, 0.f, 0.f};
    }
    for (int u = tid; u < CH * NROW * 24; u += THREADS) {
        int j = u / (NROW * 24);
        int v = u - j * (NROW * 24);
        int r = v / 24;
        int q = v - r * 24;
        int y2 = y + 2 * (dyg * NROW + r) - 20;
        if (y2 < 0 || y2 >= H_)
            ((float4*)&s2[j][r][0])[5 + q] = float4{0.f, 0.f, 0.f, 0.f};
    }

    const float* g1 = nullptr;
    float4* l1 = nullptr;
    if (tid < CH * 24) {
        int j = tid / 24, q = tid - (tid / 24) * 24;
        g1 = in1 + ((size_t)(b * C_ + j) * H_ + y) * W_ + q * 4;
        l1 = ((float4*)&s1[j][0]) + q;
    }
    const float* g2[3];
    float4*      l2[3];
    bool         v2[3];
    #pragma unroll
    for (int it = 0; it < 3; ++it) {
        int u = tid + it * THREADS;
        bool ok = (u < CH * NROW * 24);
        int uc = ok ? u : 0;
        int j = uc / (NROW * 24);
        int v = uc - j * (NROW * 24);
        int r = v / 24;
        int q = v - r * 24;
        int y2 = y + 2 * (dyg * NROW + r) - 20;
        ok = ok && (y2 >= 0) && (y2 < H_);
        int y2c = ok ? y2 : 0;
        int jc  = ok ? j : 0;
        g2[it] = in2 + ((size_t)(b * C_ + jc) * H_ + y2c) * W_ + (ok ? q : 0) * 4;
        l2[it] = ((float4*)&s2[jc][ok ? r : 0][0]) + 5 + (ok ? q : 0);
        v2[it] = ok;
    }

    const int dyj  = tid / 36;
    const int tile = tid - dyj * 36;
    const int tx   = tile % 12;
    const int tdx  = tile / 12;
    const int x0   = tx * 8;
    const int dx0  = tdx * 8;
    const bool active = (tid < NROW * 36);

    float acc[8][8];
    #pragma unroll
    for (int k = 0; k < 8; ++k)
        #pragma unroll
        for (int i = 0; i < 8; ++i) acc[k][i] = 0.f;

    constexpr size_t cstride = (size_t)CH * H_ * W_;

    for (int cc = 0; cc < C_; cc += CH) {
        __syncthreads();
        if (g1) *l1 = *(const float4*)g1;
        #pragma unroll
        for (int it = 0; it < 3; ++it)
            if (v2[it]) *l2[it] = *(const float4*)g2[it];
        __syncthreads();

        if (active) {
            #pragma unroll
            for (int j = 0; j < CH; ++j) {
                float a[8];
                float w[24];
                *(float4*)&a[0] = *(const float4*)&s1[j][x0];
                *(float4*)&a[4] = *(const float4*)&s1[j][x0 + 4];
                const float* brow = &s2[j][dyj][x0 + 2 * dx0];
                #pragma unroll
                for (int q = 0; q < 6; ++q)
                    *(float4*)&w[4 * q] = *(const float4*)&brow[4 * q];
                #pragma unroll
                for (int k = 0; k < 8; ++k)
                    #pragma unroll
                    for (int i = 0; i < 8; ++i)
                        acc[k][i] = fmaf(a[i], w[i + 2 * k], acc[k][i]);
            }
        }
        if (g1) g1 += cstride;
        #pragma unroll
        for (int it = 0; it < 3; ++it) g2[it] += cstride;
    }

    if (active) {
        const int dy = dyg * NROW + dyj;
        const float sc = 1.0f / 256.0f;
        #pragma unroll
        for (int k = 0; k < 8; ++k) {
            int dx = dx0 + k;
            if (dx < D_) {
                int d = dy * D_ + dx;
                float* po = out + ((size_t)(b * (D_ * D_) + d) * H_ + y) * W_ + x0;
                float4 v0{acc[k][0] * sc, acc[k][1] * sc, acc[k][2] * sc, acc[k][3] * sc};
                float4 v1{acc[k][4] * sc, acc[k][5] * sc, acc[k][6] * sc, acc[k][7] * sc};
                ((float4*)po)[0] = v0;
                ((float4*)po)[1] = v1;
            }
        }
    }
}

extern "C" void kernel_launch(void* const* d_in, const int* in_sizes, int n_in,
                              void* d_out, int out_size, void* d_ws, size_t ws_size,
                              hipStream_t stream) {
    const float* in1 = (const float*)d_in[0];
    const float* in2 = (const float*)d_in[1];
    float* out = (float*)d_out;
    (void)in_sizes; (void)n_in; (void)out_size;

    constexpr size_t WSA_BYTES = (size_t)8 * 64 * 2 * 48 * 256 * 2;   // 25,165,824
    constexpr size_t WSW_BYTES = (size_t)8 * 64 * 2 * 80 * 256 * 2;   // 41,943,040

    if (ws_size >= WSA_BYTES + WSW_BYTES) {
        short* wsA = (short*)d_ws;
        short* wsW = (short*)((char*)d_ws + WSA_BYTES);
        convert_kernel<<<dim3(4096), dim3(256), 0, stream>>>(in1, in2, wsA, wsW);
        corr_mfma<<<dim3(8 * 2 * 3 * 64), dim3(256), 0, stream>>>(wsA, wsW, out);
    } else {
        corr_fp32<<<dim3(B_ * H_ * NDYG), dim3(THREADS), 0, stream>>>(in1, in2, out);
    }
}